// Round 4
// baseline (387.516 us; speedup 1.0000x reference)
//
#include <hip/hip_runtime.h>
#include <hip/hip_bf16.h>

// Problem constants: B=4, S=1024, DIM=2048, H=32, KVH=8, D=64, REP=4
// qkv fused layout per row (4096 rows): [Q: h*64+d (0..2047) | K: 2048+hk*64+d | V: 2560+hk*64+d]
// Vt layout (aliases xb after QKV GEMM): Vt[b*512 + hk*64 + d][s=1024] bf16

#define DEVINL __device__ __forceinline__

typedef __attribute__((ext_vector_type(8))) short    bf16x8;
typedef __attribute__((ext_vector_type(4))) short    bf16x4;
typedef __attribute__((ext_vector_type(4))) float    f32x4;
typedef __attribute__((ext_vector_type(8))) unsigned short u16x8;

DEVINL unsigned short f2bf(float f) {            // RNE fp32 -> bf16
  unsigned u = __float_as_uint(f);
  u += 0x7FFFu + ((u >> 16) & 1u);
  return (unsigned short)(u >> 16);
}
DEVINL float bf2f(unsigned short h) { return __uint_as_float((unsigned)h << 16); }

DEVINL void gload_lds16(const void* g, void* l) {  // async global->LDS, 16B/lane
  __builtin_amdgcn_global_load_lds((const __attribute__((address_space(1))) void*)g,
                                   (__attribute__((address_space(3))) void*)l, 16, 0, 0);
}

// ---------------- fp32 -> bf16 convert (x), 8 elems/thread ----------------
__global__ __launch_bounds__(256) void k_cvt_bf16(const float* __restrict__ in,
                                                  unsigned short* __restrict__ out) {
  long long i = (long long)blockIdx.x * 256 + threadIdx.x;
  const float4* p = (const float4*)(in + i * 8);
  float4 a = p[0], b = p[1];
  u16x8 r = { f2bf(a.x), f2bf(a.y), f2bf(a.z), f2bf(a.w),
              f2bf(b.x), f2bf(b.y), f2bf(b.z), f2bf(b.w) };
  *(u16x8*)(out + i * 8) = r;
}

// ------------- weight transpose+convert: fp32 (K,N) -> bf16 (N,K) -------------
__global__ __launch_bounds__(256) void k_transpose_w(const float* __restrict__ in,
                                                     unsigned short* __restrict__ out,
                                                     int K, int N) {
  __shared__ float tile[32][33];                  // +1 pad: conflict-free transpose
  int ntiles = N >> 5;
  int bx = blockIdx.x % ntiles, by = blockIdx.x / ntiles;
  int tx = threadIdx.x & 31, ty = threadIdx.x >> 5;
  int n0 = bx * 32, k0 = by * 32;
#pragma unroll
  for (int i = 0; i < 32; i += 8) tile[ty + i][tx] = in[(long long)(k0 + ty + i) * N + n0 + tx];
  __syncthreads();
#pragma unroll
  for (int i = 0; i < 32; i += 8) out[(long long)(n0 + ty + i) * K + k0 + tx] = f2bf(tile[tx][ty + i]);
}

// ------------- V transpose: qkv cols 2560.. -> Vt[b*512+hd][s] -------------
__global__ __launch_bounds__(256) void k_transpose_v(const unsigned short* __restrict__ qkv,
                                                     unsigned short* __restrict__ Vt) {
  __shared__ unsigned short tile[32][33];
  int bidx = blockIdx.x;                          // 4 b * 32 s-tiles * 16 hd-tiles
  int b = bidx >> 9;
  int r2 = bidx & 511;
  int st = r2 >> 4, ht = r2 & 15;
  int tx = threadIdx.x & 31, ty = threadIdx.x >> 5;
  int s0 = st * 32, hd0 = ht * 32;
#pragma unroll
  for (int i = 0; i < 32; i += 8)
    tile[ty + i][tx] = qkv[(long long)(b * 1024 + s0 + ty + i) * 3072 + 2560 + hd0 + tx];
  __syncthreads();
#pragma unroll
  for (int i = 0; i < 32; i += 8)
    Vt[(long long)(b * 512 + hd0 + ty + i) * 1024 + s0 + tx] = tile[tx][ty + i];
}

// ------------- RoPE in-place on qkv rows: Q cols 0..2047, K cols 2048..2559 -------------
__global__ __launch_bounds__(256) void k_rope(unsigned short* __restrict__ qkv,
                                              const float* __restrict__ cosT,
                                              const float* __restrict__ sinT) {
  int idx = blockIdx.x * 256 + threadIdx.x;       // 4096 rows * 320 chunks of 8 cols
  int row = idx / 320;
  int c8  = (idx % 320) * 8;
  int s   = row & 1023;
  int i0  = (c8 & 63) >> 1;                       // pair index within head (4 pairs/chunk)
  unsigned short* p = qkv + (long long)row * 3072 + c8;
  u16x8 v = *(u16x8*)p;
  float4 cv = *(const float4*)&cosT[s * 32 + i0];
  float4 sv = *(const float4*)&sinT[s * 32 + i0];
  float cc[4] = {cv.x, cv.y, cv.z, cv.w};
  float ss[4] = {sv.x, sv.y, sv.z, sv.w};
  u16x8 o;
#pragma unroll
  for (int j = 0; j < 4; j++) {
    float a = bf2f((unsigned short)v[2 * j]), b = bf2f((unsigned short)v[2 * j + 1]);
    o[2 * j]     = (short)f2bf(a * cc[j] - b * ss[j]);
    o[2 * j + 1] = (short)f2bf(a * ss[j] + b * cc[j]);
  }
  *(u16x8*)p = o;
}

// ------------- m97-style GEMM: C[M,N] = A[M,K] * Bt[N,K]^T, 128x128 tile, BK=32 -------------
template <int F32OUT>
__global__ __launch_bounds__(256) void k_gemm_bt(const unsigned short* __restrict__ A,
                                                 const unsigned short* __restrict__ Bt,
                                                 void* __restrict__ Cout, int N, int K) {
  __shared__ unsigned short As[128 * 32];
  __shared__ unsigned short Bs[128 * 32];
  int nbn = N >> 7;
  int bm = (blockIdx.x / nbn) << 7, bn = (blockIdx.x % nbn) << 7;
  int t = threadIdx.x, w = t >> 6, l = t & 63, g = l >> 4, lr = l & 15;
  int wm = (w >> 1) << 6, wn = (w & 1) << 6;
  f32x4 acc[4][4] = {};
  const unsigned short* Ab = A + (long long)bm * K;
  const unsigned short* Bb = Bt + (long long)bn * K;
  for (int k0 = 0; k0 < K; k0 += 32) {
    __syncthreads();
#pragma unroll
    for (int i = 0; i < 2; i++) {                  // 2 insts each for A,B: 4KB per inst
      int e = i * 2048 + t * 8;
      int row = e >> 5, col = e & 31;
      gload_lds16(Ab + (long long)row * K + k0 + col, (char*)As + i * 4096 + w * 1024);
      gload_lds16(Bb + (long long)row * K + k0 + col, (char*)Bs + i * 4096 + w * 1024);
    }
    __syncthreads();                               // drains vmcnt -> tiles ready
    bf16x8 a[4], b[4];
#pragma unroll
    for (int mi = 0; mi < 4; mi++) a[mi] = *(const bf16x8*)&As[(wm + mi * 16 + lr) * 32 + g * 8];
#pragma unroll
    for (int ni = 0; ni < 4; ni++) b[ni] = *(const bf16x8*)&Bs[(wn + ni * 16 + lr) * 32 + g * 8];
#pragma unroll
    for (int mi = 0; mi < 4; mi++)
#pragma unroll
      for (int ni = 0; ni < 4; ni++)
        acc[mi][ni] = __builtin_amdgcn_mfma_f32_16x16x32_bf16(a[mi], b[ni], acc[mi][ni], 0, 0, 0);
  }
#pragma unroll
  for (int mi = 0; mi < 4; mi++)
#pragma unroll
    for (int ni = 0; ni < 4; ni++)
#pragma unroll
      for (int r = 0; r < 4; r++) {
        int row = bm + wm + mi * 16 + g * 4 + r;   // C/D: col=lane&15, row=(lane>>4)*4+r
        int col = bn + wn + ni * 16 + lr;
        if (F32OUT) ((float*)Cout)[(long long)row * N + col] = acc[mi][ni][r];
        else ((unsigned short*)Cout)[(long long)row * N + col] = f2bf(acc[mi][ni][r]);
      }
}

// ------------- causal GQA flash attention, per-wave 16-q tile, no LDS, no barriers -----
// S^T = mfma(K,Q) with PERMUTED K rows: lane loads K row sigma(kc,c) =
// (kc>>1)*32 + (c>>2)*8 + (kc&1)*4 + (c&3), so S^T C-row r of chunk kc is key
// (kc>>1)*32 + g*8 + (kc&1)*4 + r  ->  lane g holds P for keys kp*32+g*8+j (contiguous!).
// PV B-frag is ONE bf16x8 load from transposed-V. K double-buffered in regs (prefetch),
// fast exp2/cvt_pk softmax, defer-max rescale (T13, THR=8).
DEVINL void load_k8(const unsigned short* Kc, int kvt, bf16x8 k[8]) {
#pragma unroll
  for (int kc = 0; kc < 4; kc++) {
    int roff = (kvt * 64 + (kc >> 1) * 32 + (kc & 1) * 4) * 3072;
    k[kc * 2]     = *(const bf16x8*)(Kc + roff);
    k[kc * 2 + 1] = *(const bf16x8*)(Kc + roff + 32);
  }
}
DEVINL void load_v8(const unsigned short* const Vr[4], int kvt, bf16x8 v[8]) {
#pragma unroll
  for (int kp = 0; kp < 2; kp++)
#pragma unroll
    for (int dt = 0; dt < 4; dt++)
      v[kp * 4 + dt] = *(const bf16x8*)(Vr[dt] + kvt * 64 + kp * 32);
}

template <bool LAST>
DEVINL void step_compute(int kvt, int g, int qglob, bool kp1,
                         const bf16x8 kcur[8], const bf16x8 vv[8],
                         const bf16x8& q0, const bf16x8& q1,
                         f32x4 acc[4], float& m, float& lsum) {
  const float SC = 0.125f * 1.44269504f;           // scale * log2(e)
  float p[16];
#pragma unroll
  for (int kc = 0; kc < 4; kc++) {
    if (LAST && kc >= 2 && !kp1) {                 // whole 32-key half above diagonal
#pragma unroll
      for (int r = 0; r < 4; r++) p[kc * 4 + r] = -1e30f;
      continue;
    }
    f32x4 s4 = {0.f, 0.f, 0.f, 0.f};
    s4 = __builtin_amdgcn_mfma_f32_16x16x32_bf16(kcur[kc * 2], q0, s4, 0, 0, 0);
    s4 = __builtin_amdgcn_mfma_f32_16x16x32_bf16(kcur[kc * 2 + 1], q1, s4, 0, 0, 0);
#pragma unroll
    for (int r = 0; r < 4; r++) {
      int key = kvt * 64 + (kc >> 1) * 32 + g * 8 + (kc & 1) * 4 + r;
      p[kc * 4 + r] = (LAST && key > qglob) ? -1e30f : s4[r];
    }
  }
  float tmax = p[0];
#pragma unroll
  for (int i = 1; i < 16; i++) tmax = fmaxf(tmax, p[i]);
  tmax = fmaxf(tmax, __shfl_xor(tmax, 16));        // reduce over g-groups (same c)
  tmax = fmaxf(tmax, __shfl_xor(tmax, 32));
  // defer-max: rescale only if some lane's max grew past THR=8 (in log2 units)
  if (!__all((tmax - m) * SC <= 8.f)) {
    float mnew = fmaxf(m, tmax);
    float fac = __builtin_amdgcn_exp2f((m - mnew) * SC);
#pragma unroll
    for (int r = 0; r < 4; r++) {                  // factor for q=g*4+r lives at lane g*4+r
      float fr = __shfl(fac, g * 4 + r);
#pragma unroll
      for (int dt = 0; dt < 4; dt++) acc[dt][r] *= fr;
    }
    lsum *= fac;
    m = mnew;
  }
  float msc = m * SC;
  float ps = 0.f;
#pragma unroll
  for (int i = 0; i < 16; i++) {
    p[i] = __builtin_amdgcn_exp2f(__builtin_fmaf(p[i], SC, -msc));
    ps += p[i];
  }
  ps += __shfl_xor(ps, 16);
  ps += __shfl_xor(ps, 32);
  lsum += ps;
  union { int w[4]; bf16x8 v; } pa[2];
#pragma unroll
  for (int i = 0; i < 8; i++)                      // pack P to bf16 pairs: 1 instr / 2 vals
    asm("v_cvt_pk_bf16_f32 %0, %1, %2" : "=v"(pa[i >> 2].w[i & 3]) : "v"(p[2 * i]), "v"(p[2 * i + 1]));
#pragma unroll
  for (int kp = 0; kp < 2; kp++) {
    if (LAST && kp == 1 && !kp1) break;
#pragma unroll
    for (int dt = 0; dt < 4; dt++)
      acc[dt] = __builtin_amdgcn_mfma_f32_16x16x32_bf16(pa[kp].v, vv[kp * 4 + dt], acc[dt], 0, 0, 0);
  }
}

__global__ __launch_bounds__(256) void k_attn(const unsigned short* __restrict__ qkv,
                                              const unsigned short* __restrict__ Vt,
                                              unsigned short* __restrict__ outO) {
  int t = threadIdx.x, w = t >> 6, l = t & 63, g = l >> 4, c = l & 15;
  // task decode: heavy diagonal first; 4 waves/block = 4 q-heads of SAME kv-head, same q-tile
  int task = blockIdx.x * 4 + w;                   // 8192 tasks
  int qt16 = 63 - (task >> 7);                     // q-tile of 16 rows, descending
  int rem  = task & 127;
  int h = rem & 31, b = rem >> 5, hk = h >> 2;
  const unsigned short* qptr = qkv + (long long)(b * 1024 + qt16 * 16 + c) * 3072 + h * 64;
  bf16x8 q0 = *(const bf16x8*)(qptr + g * 8);
  bf16x8 q1 = *(const bf16x8*)(qptr + 32 + g * 8);
  int cpart = (c >> 2) * 8 + (c & 3);              // K-row permutation, lane part
  const unsigned short* Kc = qkv + (long long)b * 1024 * 3072 + 2048 + hk * 64
                           + (long long)cpart * 3072 + g * 8;
  const unsigned short* Vr[4];
#pragma unroll
  for (int dt = 0; dt < 4; dt++)
    Vr[dt] = Vt + (long long)((b * 8 + hk) * 64 + dt * 16 + c) * 1024 + g * 8;
  f32x4 acc[4] = {};
  float m = -1e30f, lsum = 0.f;
  int qglob = qt16 * 16 + c;
  int lastkvt = qt16 >> 2;
  bool kp1last = (qt16 & 3) >= 2;
  bf16x8 kcur[8];
  load_k8(Kc, 0, kcur);
#pragma unroll 2
  for (int kvt = 0; kvt < lastkvt; ++kvt) {
    bf16x8 vv[8], kn[8];
    load_v8(Vr, kvt, vv);                          // issue early: used after QK+softmax
    load_k8(Kc, kvt + 1, kn);                      // prefetch next K under this step
    step_compute<false>(kvt, g, qglob, true, kcur, vv, q0, q1, acc, m, lsum);
#pragma unroll
    for (int i = 0; i < 8; i++) kcur[i] = kn[i];
  }
  {
    bf16x8 vv[8];
    load_v8(Vr, lastkvt, vv);
    step_compute<true>(lastkvt, g, qglob, kp1last, kcur, vv, q0, q1, acc, m, lsum);
  }
  // epilogue: normalize rows, write bf16 (B,S,H*D)
#pragma unroll
  for (int r = 0; r < 4; r++) {
    float li = __builtin_amdgcn_rcpf(__shfl(lsum, g * 4 + r));
    int qg = qt16 * 16 + g * 4 + r;
#pragma unroll
    for (int dt = 0; dt < 4; dt++)
      outO[(long long)(b * 1024 + qg) * 2048 + h * 64 + dt * 16 + c] = f2bf(acc[dt][r] * li);
  }
}

extern "C" void kernel_launch(void* const* d_in, const int* in_sizes, int n_in,
                              void* d_out, int out_size, void* d_ws, size_t ws_size,
                              hipStream_t stream) {
  const float* x  = (const float*)d_in[0];
  const float* fc = (const float*)d_in[1];
  const float* fs = (const float*)d_in[2];
  const float* wq = (const float*)d_in[3];
  const float* wk = (const float*)d_in[4];
  const float* wv = (const float*)d_in[5];
  const float* wo = (const float*)d_in[6];
  float* out = (float*)d_out;

  // ws layout (bf16 elems), total ~76 MiB
  unsigned short* xb    = (unsigned short*)d_ws;                  // 4096x2048 (dead after QKV GEMM)
  unsigned short* wqkvT = xb + (size_t)4096 * 2048;               // 3072x2048 (wq^T|wk^T|wv^T)
  unsigned short* woT   = wqkvT + (size_t)3072 * 2048;            // 2048x2048
  unsigned short* qkv   = woT + (size_t)2048 * 2048;              // 4096x3072
  unsigned short* attnO = qkv + (size_t)4096 * 3072;              // 4096x2048
  unsigned short* Vt    = xb;                                     // 2048x1024, aliases dead xb

  k_cvt_bf16<<<4096, 256, 0, stream>>>(x, xb);                    // 8M elems
  k_transpose_w<<<4096, 256, 0, stream>>>(wq, wqkvT, 2048, 2048);
  k_transpose_w<<<1024, 256, 0, stream>>>(wk, wqkvT + (size_t)2048 * 2048, 2048, 512);
  k_transpose_w<<<1024, 256, 0, stream>>>(wv, wqkvT + (size_t)2560 * 2048, 2048, 512);
  k_transpose_w<<<4096, 256, 0, stream>>>(wo, woT, 2048, 2048);
  k_gemm_bt<0><<<32 * 24, 256, 0, stream>>>(xb, wqkvT, qkv, 3072, 2048);   // QKV proj
  k_transpose_v<<<2048, 256, 0, stream>>>(qkv, Vt);               // V -> Vt (xb now dead)
  k_rope<<<5120, 256, 0, stream>>>(qkv, fc, fs);
  k_attn<<<2048, 256, 0, stream>>>(qkv, Vt, attnO);               // 8192 wave-tasks
  k_gemm_bt<1><<<32 * 16, 256, 0, stream>>>(attnO, woT, out, 2048, 2048);  // O proj -> fp32
}

// Round 5
// 299.183 us; speedup vs baseline: 1.2953x; 1.2953x over previous
//
#include <hip/hip_runtime.h>
#include <hip/hip_bf16.h>

// Problem constants: B=4, S=1024, DIM=2048, H=32, KVH=8, D=64, REP=4
// qkv fused layout per row (4096 rows): [Q: h*64+d (0..2047) | K: 2048+hk*64+d | V: 2560+hk*64+d]
// Vt layout (aliases xb after QKV GEMM): Vt[b*512 + hk*64 + d][s=1024] bf16

#define DEVINL __device__ __forceinline__

typedef __attribute__((ext_vector_type(8))) short    bf16x8;
typedef __attribute__((ext_vector_type(4))) float    f32x4;
typedef __attribute__((ext_vector_type(8))) unsigned short u16x8;

DEVINL unsigned short f2bf(float f) {            // RNE fp32 -> bf16
  unsigned u = __float_as_uint(f);
  u += 0x7FFFu + ((u >> 16) & 1u);
  return (unsigned short)(u >> 16);
}
DEVINL float bf2f(unsigned short h) { return __uint_as_float((unsigned)h << 16); }

DEVINL void gload_lds16(const void* g, void* l) {  // async global->LDS, 16B/lane
  __builtin_amdgcn_global_load_lds((const __attribute__((address_space(1))) void*)g,
                                   (__attribute__((address_space(3))) void*)l, 16, 0, 0);
}

// ---------------- fp32 -> bf16 convert (x), 8 elems/thread ----------------
__global__ __launch_bounds__(256) void k_cvt_bf16(const float* __restrict__ in,
                                                  unsigned short* __restrict__ out) {
  long long i = (long long)blockIdx.x * 256 + threadIdx.x;
  const float4* p = (const float4*)(in + i * 8);
  float4 a = p[0], b = p[1];
  u16x8 r = { f2bf(a.x), f2bf(a.y), f2bf(a.z), f2bf(a.w),
              f2bf(b.x), f2bf(b.y), f2bf(b.z), f2bf(b.w) };
  *(u16x8*)(out + i * 8) = r;
}

// ------------- weight transpose+convert: fp32 (K,N) -> bf16 (N,K) -------------
__global__ __launch_bounds__(256) void k_transpose_w(const float* __restrict__ in,
                                                     unsigned short* __restrict__ out,
                                                     int K, int N) {
  __shared__ float tile[32][33];                  // +1 pad: conflict-free transpose
  int ntiles = N >> 5;
  int bx = blockIdx.x % ntiles, by = blockIdx.x / ntiles;
  int tx = threadIdx.x & 31, ty = threadIdx.x >> 5;
  int n0 = bx * 32, k0 = by * 32;
#pragma unroll
  for (int i = 0; i < 32; i += 8) tile[ty + i][tx] = in[(long long)(k0 + ty + i) * N + n0 + tx];
  __syncthreads();
#pragma unroll
  for (int i = 0; i < 32; i += 8) out[(long long)(n0 + ty + i) * K + k0 + tx] = f2bf(tile[tx][ty + i]);
}

// ------------- V transpose: qkv cols 2560.. -> Vt[b*512+hd][s] -------------
__global__ __launch_bounds__(256) void k_transpose_v(const unsigned short* __restrict__ qkv,
                                                     unsigned short* __restrict__ Vt) {
  __shared__ unsigned short tile[32][33];
  int bidx = blockIdx.x;                          // 4 b * 32 s-tiles * 16 hd-tiles
  int b = bidx >> 9;
  int r2 = bidx & 511;
  int st = r2 >> 4, ht = r2 & 15;
  int tx = threadIdx.x & 31, ty = threadIdx.x >> 5;
  int s0 = st * 32, hd0 = ht * 32;
#pragma unroll
  for (int i = 0; i < 32; i += 8)
    tile[ty + i][tx] = qkv[(long long)(b * 1024 + s0 + ty + i) * 3072 + 2560 + hd0 + tx];
  __syncthreads();
#pragma unroll
  for (int i = 0; i < 32; i += 8)
    Vt[(long long)(b * 512 + hd0 + ty + i) * 1024 + s0 + tx] = tile[tx][ty + i];
}

// ------------- RoPE in-place on qkv rows: Q cols 0..2047, K cols 2048..2559 -------------
__global__ __launch_bounds__(256) void k_rope(unsigned short* __restrict__ qkv,
                                              const float* __restrict__ cosT,
                                              const float* __restrict__ sinT) {
  int idx = blockIdx.x * 256 + threadIdx.x;       // 4096 rows * 320 chunks of 8 cols
  int row = idx / 320;
  int c8  = (idx % 320) * 8;
  int s   = row & 1023;
  int i0  = (c8 & 63) >> 1;                       // pair index within head (4 pairs/chunk)
  unsigned short* p = qkv + (long long)row * 3072 + c8;
  u16x8 v = *(u16x8*)p;
  float4 cv = *(const float4*)&cosT[s * 32 + i0];
  float4 sv = *(const float4*)&sinT[s * 32 + i0];
  float cc[4] = {cv.x, cv.y, cv.z, cv.w};
  float ss[4] = {sv.x, sv.y, sv.z, sv.w};
  u16x8 o;
#pragma unroll
  for (int j = 0; j < 4; j++) {
    float a = bf2f((unsigned short)v[2 * j]), b = bf2f((unsigned short)v[2 * j + 1]);
    o[2 * j]     = (short)f2bf(a * cc[j] - b * ss[j]);
    o[2 * j + 1] = (short)f2bf(a * ss[j] + b * cc[j]);
  }
  *(u16x8*)p = o;
}

// ------------- m97-style GEMM: C[M,N] = A[M,K] * Bt[N,K]^T, 128x128 tile, BK=32 -------------
template <int F32OUT>
__global__ __launch_bounds__(256) void k_gemm_bt(const unsigned short* __restrict__ A,
                                                 const unsigned short* __restrict__ Bt,
                                                 void* __restrict__ Cout, int N, int K) {
  __shared__ unsigned short As[128 * 32];
  __shared__ unsigned short Bs[128 * 32];
  int nbn = N >> 7;
  int bm = (blockIdx.x / nbn) << 7, bn = (blockIdx.x % nbn) << 7;
  int t = threadIdx.x, w = t >> 6, l = t & 63, g = l >> 4, lr = l & 15;
  int wm = (w >> 1) << 6, wn = (w & 1) << 6;
  f32x4 acc[4][4] = {};
  const unsigned short* Ab = A + (long long)bm * K;
  const unsigned short* Bb = Bt + (long long)bn * K;
  for (int k0 = 0; k0 < K; k0 += 32) {
    __syncthreads();
#pragma unroll
    for (int i = 0; i < 2; i++) {                  // 2 insts each for A,B: 4KB per inst
      int e = i * 2048 + t * 8;
      int row = e >> 5, col = e & 31;
      gload_lds16(Ab + (long long)row * K + k0 + col, (char*)As + i * 4096 + w * 1024);
      gload_lds16(Bb + (long long)row * K + k0 + col, (char*)Bs + i * 4096 + w * 1024);
    }
    __syncthreads();                               // drains vmcnt -> tiles ready
    bf16x8 a[4], b[4];
#pragma unroll
    for (int mi = 0; mi < 4; mi++) a[mi] = *(const bf16x8*)&As[(wm + mi * 16 + lr) * 32 + g * 8];
#pragma unroll
    for (int ni = 0; ni < 4; ni++) b[ni] = *(const bf16x8*)&Bs[(wn + ni * 16 + lr) * 32 + g * 8];
#pragma unroll
    for (int mi = 0; mi < 4; mi++)
#pragma unroll
      for (int ni = 0; ni < 4; ni++)
        acc[mi][ni] = __builtin_amdgcn_mfma_f32_16x16x32_bf16(a[mi], b[ni], acc[mi][ni], 0, 0, 0);
  }
#pragma unroll
  for (int mi = 0; mi < 4; mi++)
#pragma unroll
    for (int ni = 0; ni < 4; ni++)
#pragma unroll
      for (int r = 0; r < 4; r++) {
        int row = bm + wm + mi * 16 + g * 4 + r;   // C/D: col=lane&15, row=(lane>>4)*4+r
        int col = bn + wn + ni * 16 + lr;
        if (F32OUT) ((float*)Cout)[(long long)row * N + col] = acc[mi][ni][r];
        else ((unsigned short*)Cout)[(long long)row * N + col] = f2bf(acc[mi][ni][r]);
      }
}

// ------------- causal GQA flash attention, 4 waves/block sharing K/V via LDS -----------
// Waves 0..3 of a block = 4 q-heads of the SAME kv-head, same 16-q tile.
// K tile [64 keys][64 d] and V tile (from Vt) [64 d][64 keys] staged per step via
// global_load_lds (linear LDS dest, pre-swizzled global source — rule #21).
// Chunk swizzles (16B chunks, 8/row): K: ch ^= (row&3)|(((row>>3)&1)<<2); V: ch ^= row&7.
// Both chosen so each consecutive-8-lane ds_read_b128 group covers all 8 bank-quads.
// S^T = mfma(K,Q) with permuted K rows so lane g holds P for keys kp*32+g*8+j.
DEVINL void stage_kv(const unsigned short* Ksrc, const unsigned short* Vsrc,
                     unsigned short* Kdst, unsigned short* Vdst, int w, int l) {
  int lr = l >> 3, lc = l & 7;                     // lane -> row-in-group, chunk
#pragma unroll
  for (int i = 0; i < 4; i++) {
    int j = (w & 1) * 4 + i;                       // 1KB instr index within tile
    int row = j * 8 + lr;
    if (w < 2) {                                   // waves 0,1: K tile (row stride 3072)
      int gch = lc ^ ((lr & 3) | ((j & 1) << 2));  // fK(row)=(row&3)|(((row>>3)&1)<<2)
      gload_lds16(Ksrc + (long long)row * 3072 + gch * 8, (char*)Kdst + j * 1024);
    } else {                                       // waves 2,3: V tile (row stride 1024)
      int gch = lc ^ lr;                           // fV(row)=row&7
      gload_lds16(Vsrc + (long long)row * 1024 + gch * 8, (char*)Vdst + j * 1024);
    }
  }
}

template <bool LAST>
DEVINL void step_compute(int kvt, int g, int c, int qglob, bool kp1,
                         const unsigned short* Kb, const unsigned short* Vb,
                         const bf16x8& q0, const bf16x8& q1,
                         f32x4 acc[4], float& m, float& lsum) {
  const float SC = 0.125f * 1.44269504f;           // scale * log2(e)
  int fk = (c & 3) | (((c >> 2) & 1) << 2);        // fK of this lane's K rows
  int fv = c & 7;                                  // fV of this lane's V rows
  float p[16];
#pragma unroll
  for (int kc = 0; kc < 4; kc++) {
    if (LAST && kc >= 2 && !kp1) {                 // whole 32-key half above diagonal
#pragma unroll
      for (int r = 0; r < 4; r++) p[kc * 4 + r] = -1e30f;
      continue;
    }
    int row = (kc >> 1) * 32 + (kc & 1) * 4 + ((c >> 2) << 3) + (c & 3);
    bf16x8 k0 = *(const bf16x8*)((const char*)Kb + row * 128 + ((g ^ fk) << 4));
    bf16x8 k1 = *(const bf16x8*)((const char*)Kb + row * 128 + (((g + 4) ^ fk) << 4));
    f32x4 s4 = {0.f, 0.f, 0.f, 0.f};
    s4 = __builtin_amdgcn_mfma_f32_16x16x32_bf16(k0, q0, s4, 0, 0, 0);
    s4 = __builtin_amdgcn_mfma_f32_16x16x32_bf16(k1, q1, s4, 0, 0, 0);
#pragma unroll
    for (int r = 0; r < 4; r++) {
      int key = kvt * 64 + (kc >> 1) * 32 + g * 8 + (kc & 1) * 4 + r;
      p[kc * 4 + r] = (LAST && key > qglob) ? -1e30f : s4[r];
    }
  }
  bf16x8 vf[8];                                    // V frags early: latency hides under softmax
#pragma unroll
  for (int kp = 0; kp < 2; kp++)
#pragma unroll
    for (int dt = 0; dt < 4; dt++) {
      int row = dt * 16 + c;
      vf[kp * 4 + dt] = *(const bf16x8*)((const char*)Vb + row * 128 + (((kp * 4 + g) ^ fv) << 4));
    }
  float tmax = p[0];
#pragma unroll
  for (int i = 1; i < 16; i++) tmax = fmaxf(tmax, p[i]);
  tmax = fmaxf(tmax, __shfl_xor(tmax, 16));        // reduce over g-groups (same c)
  tmax = fmaxf(tmax, __shfl_xor(tmax, 32));
  // defer-max: rescale only if some lane's max grew past THR=8 (in log2 units)
  if (!__all((tmax - m) * SC <= 8.f)) {
    float mnew = fmaxf(m, tmax);
    float fac = __builtin_amdgcn_exp2f((m - mnew) * SC);
#pragma unroll
    for (int r = 0; r < 4; r++) {                  // factor for q=g*4+r lives at lane g*4+r
      float fr = __shfl(fac, g * 4 + r);
#pragma unroll
      for (int dt = 0; dt < 4; dt++) acc[dt][r] *= fr;
    }
    lsum *= fac;
    m = mnew;
  }
  float msc = m * SC;
  float ps = 0.f;
#pragma unroll
  for (int i = 0; i < 16; i++) {
    p[i] = __builtin_amdgcn_exp2f(__builtin_fmaf(p[i], SC, -msc));
    ps += p[i];
  }
  ps += __shfl_xor(ps, 16);
  ps += __shfl_xor(ps, 32);
  lsum += ps;
  union { int w[4]; bf16x8 v; } pa[2];
#pragma unroll
  for (int i = 0; i < 8; i++)                      // pack P to bf16 pairs: 1 instr / 2 vals
    asm("v_cvt_pk_bf16_f32 %0, %1, %2" : "=v"(pa[i >> 2].w[i & 3]) : "v"(p[2 * i]), "v"(p[2 * i + 1]));
#pragma unroll
  for (int kp = 0; kp < 2; kp++) {
    if (LAST && kp == 1 && !kp1) break;
#pragma unroll
    for (int dt = 0; dt < 4; dt++)
      acc[dt] = __builtin_amdgcn_mfma_f32_16x16x32_bf16(pa[kp].v, vf[kp * 4 + dt], acc[dt], 0, 0, 0);
  }
}

__global__ __launch_bounds__(256) void k_attn(const unsigned short* __restrict__ qkv,
                                              const unsigned short* __restrict__ Vt,
                                              unsigned short* __restrict__ outO) {
  __shared__ unsigned short KV[2][2][4096];        // [dbuf][K,V][8KB tile]
  int t = threadIdx.x, w = t >> 6, l = t & 63, g = l >> 4, c = l & 15;
  // task decode: heavy diagonal first; waves of a block share (b,hk,qt16), h=hk*4+w
  int task = blockIdx.x * 4 + w;                   // 8192 tasks
  int qt16 = 63 - (task >> 7);                     // q-tile of 16 rows, descending
  int rem  = task & 127;
  int h = rem & 31, b = rem >> 5, hk = h >> 2;
  const unsigned short* qptr = qkv + (long long)(b * 1024 + qt16 * 16 + c) * 3072 + h * 64;
  bf16x8 q0 = *(const bf16x8*)(qptr + g * 8);
  bf16x8 q1 = *(const bf16x8*)(qptr + 32 + g * 8);
  const unsigned short* Ksrc = qkv + (long long)b * 1024 * 3072 + 2048 + hk * 64;
  const unsigned short* Vsrc = Vt + (long long)(b * 8 + hk) * 64 * 1024;
  f32x4 acc[4] = {};
  float m = -1e30f, lsum = 0.f;
  int qglob = qt16 * 16 + c;
  int lastkvt = qt16 >> 2;
  bool kp1last = (qt16 & 3) >= 2;
  stage_kv(Ksrc, Vsrc, KV[0][0], KV[0][1], w, l);  // tile 0
  for (int kvt = 0; kvt <= lastkvt; ++kvt) {
    int cur = kvt & 1;
    __syncthreads();                               // drains vmcnt -> buf[cur] ready
    if (kvt < lastkvt)                             // prefetch next tile under compute
      stage_kv(Ksrc + (long long)(kvt + 1) * 64 * 3072, Vsrc + (kvt + 1) * 64,
               KV[cur ^ 1][0], KV[cur ^ 1][1], w, l);
    if (kvt == lastkvt)
      step_compute<true >(kvt, g, c, qglob, kp1last, KV[cur][0], KV[cur][1], q0, q1, acc, m, lsum);
    else
      step_compute<false>(kvt, g, c, qglob, true,    KV[cur][0], KV[cur][1], q0, q1, acc, m, lsum);
  }
  // epilogue: normalize rows, write bf16 (B,S,H*D)
#pragma unroll
  for (int r = 0; r < 4; r++) {
    float li = __builtin_amdgcn_rcpf(__shfl(lsum, g * 4 + r));
    int qg = qt16 * 16 + g * 4 + r;
#pragma unroll
    for (int dt = 0; dt < 4; dt++)
      outO[(long long)(b * 1024 + qg) * 2048 + h * 64 + dt * 16 + c] = f2bf(acc[dt][r] * li);
  }
}

extern "C" void kernel_launch(void* const* d_in, const int* in_sizes, int n_in,
                              void* d_out, int out_size, void* d_ws, size_t ws_size,
                              hipStream_t stream) {
  const float* x  = (const float*)d_in[0];
  const float* fc = (const float*)d_in[1];
  const float* fs = (const float*)d_in[2];
  const float* wq = (const float*)d_in[3];
  const float* wk = (const float*)d_in[4];
  const float* wv = (const float*)d_in[5];
  const float* wo = (const float*)d_in[6];
  float* out = (float*)d_out;

  // ws layout (bf16 elems), total ~76 MiB
  unsigned short* xb    = (unsigned short*)d_ws;                  // 4096x2048 (dead after QKV GEMM)
  unsigned short* wqkvT = xb + (size_t)4096 * 2048;               // 3072x2048 (wq^T|wk^T|wv^T)
  unsigned short* woT   = wqkvT + (size_t)3072 * 2048;            // 2048x2048
  unsigned short* qkv   = woT + (size_t)2048 * 2048;              // 4096x3072
  unsigned short* attnO = qkv + (size_t)4096 * 3072;              // 4096x2048
  unsigned short* Vt    = xb;                                     // 2048x1024, aliases dead xb

  k_cvt_bf16<<<4096, 256, 0, stream>>>(x, xb);                    // 8M elems
  k_transpose_w<<<4096, 256, 0, stream>>>(wq, wqkvT, 2048, 2048);
  k_transpose_w<<<1024, 256, 0, stream>>>(wk, wqkvT + (size_t)2048 * 2048, 2048, 512);
  k_transpose_w<<<1024, 256, 0, stream>>>(wv, wqkvT + (size_t)2560 * 2048, 2048, 512);
  k_transpose_w<<<4096, 256, 0, stream>>>(wo, woT, 2048, 2048);
  k_gemm_bt<0><<<32 * 24, 256, 0, stream>>>(xb, wqkvT, qkv, 3072, 2048);   // QKV proj
  k_transpose_v<<<2048, 256, 0, stream>>>(qkv, Vt);               // V -> Vt (xb now dead)
  k_rope<<<5120, 256, 0, stream>>>(qkv, fc, fs);
  k_attn<<<2048, 256, 0, stream>>>(qkv, Vt, attnO);               // 2048 blocks x 4 shared waves
  k_gemm_bt<1><<<32 * 16, 256, 0, stream>>>(attnO, woT, out, 2048, 2048);  // O proj -> fp32
}